// Round 10
// baseline (581.954 us; speedup 1.0000x reference)
//
#include <hip/hip_runtime.h>

typedef unsigned short ushort_t;
typedef __attribute__((ext_vector_type(8))) short short8;
typedef __attribute__((ext_vector_type(8))) unsigned short us8v;
typedef __attribute__((ext_vector_type(4))) float f32x4;

struct __align__(4) us2 { unsigned short x, y; };

__device__ __forceinline__ float b2f(unsigned short u) {
    union { unsigned int i; float f; } v; v.i = ((unsigned int)u) << 16; return v.f;
}
__device__ __forceinline__ unsigned short f2b(float f) {
    union { float f; unsigned int i; } v; v.f = f;
    unsigned int r = (v.i + 0x7FFF + ((v.i >> 16) & 1)) >> 16;
    return (unsigned short)r;
}

// int64 path: low words carry the value (nonneg < 2^31); 8B coalesced loads
__device__ __forceinline__ void load_edge(const int* __restrict__ ei, int e, int E,
                                          int is64, int& s, int& d) {
    if (is64) {
        const long long* el = (const long long*)ei;
        s = (int)el[e]; d = (int)el[E + e];
    } else {
        s = ei[e]; d = ei[E + e];
    }
}

// detection: odd int32 words of first 512 entries all zero => int64
__device__ __forceinline__ int detect64(const int* __restrict__ ei, int t) {
    int z = 0;
    for (int i = t; i < 512; i += 256) z |= ei[2 * i + 1];
    return (__syncthreads_or(z) == 0);
}

// ---- bucket histogram (blocks < nch) + W transpose (2 extra blocks) -----
__global__ __launch_bounds__(256) void k_histT(const int* __restrict__ ei, int E,
                                               unsigned N, int* __restrict__ bhist,
                                               int BSH, int NB, int nch,
                                               const float* __restrict__ W1,
                                               const float* __restrict__ W2,
                                               ushort_t* __restrict__ WT) {
    __shared__ int lh[256];
    int t = threadIdx.x;
    int b = blockIdx.x;
    if (b >= nch) {
        const float* src = (b == nch) ? W1 : W2;
        ushort_t* dst = WT + (b - nch) * 16384;
        for (int i = t; i < 16384; i += 256) {
            int n = i >> 7, k = i & 127;
            dst[i] = f2b(src[k * 128 + n]);   // WT[n][k] = W[k][n]
        }
        return;
    }
    for (int q = t; q < NB; q += 256) lh[q] = 0;
    int is64 = detect64(ei, t);   // includes __syncthreads
    int e0 = b * 4096;
    #pragma unroll
    for (int i = 0; i < 16; ++i) {
        int e = e0 + i * 256 + t;
        if (e < E) {
            int d = is64 ? (int)((const long long*)ei)[E + e] : ei[E + e];
            if ((unsigned)d < N) atomicAdd(&lh[d >> BSH], 1);
        }
    }
    __syncthreads();
    for (int q = t; q < NB; q += 256) { int v = lh[q]; if (v) atomicAdd(&bhist[q], v); }
}

// ---- exclusive scan of bucket hist (NB <= 256), one block ---------------
__global__ void k_scanb(const int* __restrict__ bhist, int NB,
                        int* __restrict__ bkbase, int* __restrict__ bkcur) {
    __shared__ int sd[256];
    int t = threadIdx.x;
    int v0 = (t < NB) ? bhist[t] : 0;
    sd[t] = v0;
    for (int o = 1; o < 256; o <<= 1) {
        __syncthreads();
        int v = (t >= o) ? sd[t - o] : 0;
        __syncthreads();
        sd[t] += v;
    }
    __syncthreads();
    if (t < NB) { int ex = sd[t] - v0; bkbase[t] = ex; bkcur[t] = ex; }
}

// ---- fused: bucket scatter (blocks < nch) || GEMM1 unscaled (rest) ------
// GEMM1 writes xt1 in SLAB layout: xt[slab][row][16], slab = out-col / 16.
__global__ __launch_bounds__(256) void k_bg(const int* __restrict__ ei, int E,
                                            unsigned N, int* __restrict__ bkcur,
                                            int* __restrict__ bs, int* __restrict__ bd,
                                            int BSH, int NB, int nch,
                                            const float* __restrict__ x,
                                            const ushort_t* __restrict__ WT,
                                            ushort_t* __restrict__ xt, int M) {
    __shared__ __align__(16) int smem[13056];   // 52224 B union
    int t = threadIdx.x;
    int b = blockIdx.x;

    if (b < nch) {
        // ---------------- bucket scatter (proven pattern) ----------------
        int* lss = smem;             // [4096]
        int* ldd = smem + 4096;      // [4096]
        int* lhist = smem + 8192;    // [256]
        int* lcur = smem + 8448;     // [256]
        int e0 = b * 4096;
        for (int q = t; q < NB; q += 256) lhist[q] = 0;
        int is64 = detect64(ei, t);
        #pragma unroll
        for (int i = 0; i < 16; ++i) {
            int idx = i * 256 + t, e = e0 + idx;
            int s = -1, d = -1;
            if (e < E) {
                load_edge(ei, e, E, is64, s, d);
                if (!((unsigned)s < N && (unsigned)d < N)) d = -1;
            }
            lss[idx] = s; ldd[idx] = d;
            if (d >= 0) atomicAdd(&lhist[d >> BSH], 1);
        }
        __syncthreads();
        for (int q = t; q < NB; q += 256) {
            int v = lhist[q];
            lcur[q] = v ? atomicAdd(&bkcur[q], v) : 0;
        }
        __syncthreads();
        #pragma unroll
        for (int i = 0; i < 16; ++i) {
            int idx = i * 256 + t;
            int d = ldd[idx];
            if (d >= 0) {
                int p = atomicAdd(&lcur[d >> BSH], 1);
                bs[p] = lss[idx]; bd[p] = d;
            }
        }
    } else {
        // ---------------- GEMM1: xt = bf16(x @ W1), unscaled, slab out ---
        ushort_t* sA = (ushort_t*)smem;            // 64*136
        ushort_t* sW = (ushort_t*)smem + 8704;     // 128*136
        int row0 = (b - nch) * 64;
        size_t sstride = (size_t)M * 16;
        #pragma unroll
        for (int it = 0; it < 8; ++it) {
            int flat = (it * 256 + t) * 8;
            int n = flat >> 7, k = flat & 127;
            uint4 v = *(const uint4*)(WT + flat);
            *(uint4*)(&sW[n * 136 + k]) = v;
        }
        #pragma unroll
        for (int it = 0; it < 4; ++it) {
            int flat = (it * 256 + t) * 8;
            int r = flat >> 7, cc = flat & 127;
            int row = row0 + r; if (row > M - 1) row = M - 1;
            const float* p = x + (size_t)row * 128 + cc;
            float4 f0 = *(const float4*)p;
            float4 f1 = *(const float4*)(p + 4);
            ushort_t tmp[8] __attribute__((aligned(16)));
            tmp[0] = f2b(f0.x); tmp[1] = f2b(f0.y); tmp[2] = f2b(f0.z); tmp[3] = f2b(f0.w);
            tmp[4] = f2b(f1.x); tmp[5] = f2b(f1.y); tmp[6] = f2b(f1.z); tmp[7] = f2b(f1.w);
            *(uint4*)(&sA[r * 136 + cc]) = *(const uint4*)tmp;
        }
        __syncthreads();
        int w = t >> 6, lane = t & 63;
        int m = lane & 15, quad = lane >> 4;
        f32x4 acc[8] = {};
        #pragma unroll
        for (int k0 = 0; k0 < 128; k0 += 32) {
            short8 af = *(const short8*)(&sA[(w * 16 + m) * 136 + k0 + quad * 8]);
            #pragma unroll
            for (int tt = 0; tt < 8; ++tt) {
                short8 bf = *(const short8*)(&sW[(tt * 16 + m) * 136 + k0 + quad * 8]);
                acc[tt] = __builtin_amdgcn_mfma_f32_16x16x32_bf16(af, bf, acc[tt], 0, 0, 0);
            }
        }
        #pragma unroll
        for (int r = 0; r < 4; ++r) {
            int row = row0 + w * 16 + quad * 4 + r;
            if (row < M) {
                #pragma unroll
                for (int tt = 0; tt < 8; ++tt)
                    xt[(size_t)tt * sstride + (size_t)row * 16 + m] = f2b(acc[tt][r]);
            }
        }
    }
}

// ---- fused count + padded-scan/assign + fill, all bucket-local ----------
__global__ __launch_bounds__(256) void k_caf(const int* __restrict__ bs,
                                             const int* __restrict__ bd,
                                             const int* __restrict__ bkbase,
                                             const int* __restrict__ bkcur,
                                             int N, int BSH,
                                             int* __restrict__ pos,
                                             int* __restrict__ cnt,
                                             float* __restrict__ dinv,
                                             int* __restrict__ srcs) {
    __shared__ int lc[512];   // counts, then fill cursors
    __shared__ int sc[512];   // padded-count inclusive scan
    int b = blockIdx.x, t = threadIdx.x;
    int nbase = b << BSH;
    int nn = min(1 << BSH, N - nbase);
    int segbase = bkbase[b] + b * (7 << BSH);

    lc[t] = 0; lc[t + 256] = 0;
    __syncthreads();
    int s0 = bkbase[b], s1 = bkcur[b];
    for (int i = s0 + t; i < s1; i += 256) atomicAdd(&lc[bd[i] - nbase], 1);
    __syncthreads();

    int c0 = (t < nn) ? lc[t] : 0;
    int c1 = (t + 256 < nn) ? lc[t + 256] : 0;
    int p0 = (c0 + 7) & ~7;                // pad each list to multiple of 8
    int p1 = (c1 + 7) & ~7;
    sc[t] = p0; sc[t + 256] = p1;
    __syncthreads();
    for (int o = 1; o < 512; o <<= 1) {
        int v0 = (t >= o) ? sc[t - o] : 0;
        int v1 = (t + 256 >= o) ? sc[t + 256 - o] : 0;
        __syncthreads();
        sc[t] += v0; sc[t + 256] += v1;
        __syncthreads();
    }
    if (t < nn) {
        int st = segbase + sc[t] - p0;
        pos[nbase + t] = st;
        cnt[nbase + t] = c0;                       // TRUE count
        dinv[nbase + t] = rsqrtf((float)c0 + 1.0f);
        for (int q = c0; q < p0; ++q) srcs[st + q] = nbase + t;  // self pads
        lc[t] = st;
    }
    if (t + 256 < nn) {
        int st = segbase + sc[t + 256] - p1;
        pos[nbase + t + 256] = st;
        cnt[nbase + t + 256] = c1;
        dinv[nbase + t + 256] = rsqrtf((float)c1 + 1.0f);
        for (int q = c1; q < p1; ++q) srcs[st + q] = nbase + t + 256;
        lc[t + 256] = st;
    }
    __syncthreads();
    for (int i = s0 + t; i < s1; i += 256) {
        int d = bd[i];
        int p = atomicAdd(&lc[d - nbase], 1);
        srcs[p] = bs[i];
    }
}

// ---- GEMM layer 2: C = bf16(dinv * (A_slab @ W)); A and C in SLAB layout
__global__ __launch_bounds__(256) void k_gemm2(const ushort_t* __restrict__ A,
                                               const ushort_t* __restrict__ WT,
                                               ushort_t* __restrict__ C,
                                               const float* __restrict__ dinv, int M) {
    __shared__ __align__(16) ushort_t sA[64 * 136];
    __shared__ __align__(16) ushort_t sW[128 * 136];
    int t = threadIdx.x;
    int row0 = blockIdx.x * 64;
    size_t sstride = (size_t)M * 16;
    #pragma unroll
    for (int it = 0; it < 8; ++it) {
        int flat = (it * 256 + t) * 8;
        int n = flat >> 7, k = flat & 127;
        uint4 v = *(const uint4*)(WT + flat);
        *(uint4*)(&sW[n * 136 + k]) = v;
    }
    #pragma unroll
    for (int it = 0; it < 4; ++it) {
        int flat = (it * 256 + t) * 8;
        int r = flat >> 7, cc = flat & 127;
        int row = row0 + r; if (row > M - 1) row = M - 1;
        int slab = cc >> 4, off = cc & 15;
        us8v v = *(const us8v*)(A + (size_t)slab * sstride + (size_t)row * 16 + off);
        *(us8v*)(&sA[r * 136 + cc]) = v;
    }
    __syncthreads();
    int w = t >> 6, lane = t & 63;
    int m = lane & 15, quad = lane >> 4;
    f32x4 acc[8] = {};
    #pragma unroll
    for (int k0 = 0; k0 < 128; k0 += 32) {
        short8 af = *(const short8*)(&sA[(w * 16 + m) * 136 + k0 + quad * 8]);
        #pragma unroll
        for (int tt = 0; tt < 8; ++tt) {
            short8 bf = *(const short8*)(&sW[(tt * 16 + m) * 136 + k0 + quad * 8]);
            acc[tt] = __builtin_amdgcn_mfma_f32_16x16x32_bf16(af, bf, acc[tt], 0, 0, 0);
        }
    }
    #pragma unroll
    for (int r = 0; r < 4; ++r) {
        int row = row0 + w * 16 + quad * 4 + r;
        if (row < M) {
            float dd = dinv[row];
            #pragma unroll
            for (int tt = 0; tt < 8; ++tt)
                C[(size_t)tt * sstride + (size_t)row * 16 + m] = f2b(dd * acc[tt][r]);
        }
    }
}

// ---- Aggregation, feature-sliced (XCD-pinned slab per blockIdx&7) -------
// xt in slab layout [8][N][16]. Each wave: 1 destination x 1 slab;
// 8 edge-groups x 8 lanes x us2 (2 features). Each wave does 4 dests.
// WEI=true  (layer 1): o = dd*sum(dinv[s]*xt[s]) + (1-k)*dd*dd*xt[d] + b
// WEI=false (layer 2): o = dd*(sum + (1-k)*xt[d]) + b
// OBF: slab-layout bf16 out (hbf). !OBF: row-major f32 out (final).
template <bool OBF, bool WEI>
__global__ __launch_bounds__(256) void k_agg(const ushort_t* __restrict__ xt,
                                             const float* __restrict__ bias,
                                             void* __restrict__ outp,
                                             const int* __restrict__ pos,
                                             const int* __restrict__ cnts,
                                             const float* __restrict__ dinv,
                                             const int* __restrict__ srcs, int N) {
    int lane = threadIdx.x & 63;
    int wid = threadIdx.x >> 6;
    int slice = blockIdx.x & 7;              // XCD-pinned feature slab
    int dbase = (blockIdx.x >> 3) * 16;
    int g = lane >> 3;                        // edge group 0..7
    int fp = lane & 7;                        // feature pair 0..7
    size_t sstride = (size_t)N * 16;
    const ushort_t* slab = xt + (size_t)slice * sstride;
    float2 bb = *(const float2*)(bias + slice * 16 + fp * 2);

    for (int k = 0; k < 4; ++k) {
        int d = dbase + wid + k * 4;
        if (d >= N) break;                    // wave-uniform
        int c = cnts[d];                      // true count
        int cn = (c + 7) & ~7;                // padded loop bound
        float kpad = (float)(cn - c);
        int start = pos[d];
        float dd = dinv[d];
        float selfc = WEI ? (1.f - kpad) * dd * dd : (1.f - kpad) * dd;
        us2 vsv = *(const us2*)(slab + (size_t)d * 16 + fp * 2);

        float a0 = 0.f, a1 = 0.f;
        for (int base = 0; base < cn; base += 64) {
            int n = cn - base; if (n > 64) n = 64;   // multiple of 8
            int sv = 0; float wv = 1.f;
            if (lane < n) {
                sv = srcs[start + base + lane];
                if (WEI) wv = dinv[sv];
            }
            #pragma unroll 4
            for (int cc = 0; cc < n; cc += 8) {
                int s = __shfl(sv, cc + g);
                us2 v = *(const us2*)(slab + (size_t)s * 16 + fp * 2);
                if (WEI) {
                    float w = __shfl(wv, cc + g);
                    a0 += w * b2f(v.x); a1 += w * b2f(v.y);
                } else {
                    a0 += b2f(v.x); a1 += b2f(v.y);
                }
            }
        }
        // reduce across the 8 edge-groups
        a0 += __shfl_xor(a0, 8);  a1 += __shfl_xor(a1, 8);
        a0 += __shfl_xor(a0, 16); a1 += __shfl_xor(a1, 16);
        a0 += __shfl_xor(a0, 32); a1 += __shfl_xor(a1, 32);

        if (g == 0) {
            float o0 = dd * a0 + selfc * b2f(vsv.x) + bb.x;
            float o1 = dd * a1 + selfc * b2f(vsv.y) + bb.y;
            if (OBF) {
                us2 t2; t2.x = f2b(o0); t2.y = f2b(o1);
                *(us2*)((ushort_t*)outp + (size_t)slice * sstride
                        + (size_t)d * 16 + fp * 2) = t2;
            } else {
                float2 q; q.x = o0; q.y = o1;
                *(float2*)((float*)outp + (size_t)d * 128 + slice * 16 + fp * 2) = q;
            }
        }
    }
}

// ---- launch -------------------------------------------------------------

extern "C" void kernel_launch(void* const* d_in, const int* in_sizes, int n_in,
                              void* d_out, int out_size, void* d_ws, size_t ws_size,
                              hipStream_t stream) {
    const float* x  = (const float*)d_in[0];   // [N,128] f32
    const int*   ei = (const int*)d_in[1];     // [2,E] int32/int64 (detected)
    const float* W1 = (const float*)d_in[2];   // [128,128] f32
    const float* b1 = (const float*)d_in[3];   // [128] f32
    const float* W2 = (const float*)d_in[4];
    const float* b2 = (const float*)d_in[5];
    float* out = (float*)d_out;                // [N,128] f32

    const int N = in_sizes[0] / 128;
    const int E = in_sizes[1] / 2;

    // bucket size 2^BSH nodes, NB <= 256 buckets (N=100000 -> BSH=9, NB=196)
    int BSH = 9;
    int NB = (N + (1 << BSH) - 1) >> BSH;
    while (NB > 256) { BSH++; NB = (N + (1 << BSH) - 1) >> BSH; }

    char* ws = (char*)d_ws;
    size_t o = 0;
    auto take = [&](size_t bytes) { size_t r = o; o = (o + bytes + 255) & ~(size_t)255; return r; };
    size_t o_bhist  = take(256 * 4);
    size_t zero_end = o;                  // memset [0, zero_end): bhist
    size_t o_bkbase = take(256 * 4);
    size_t o_bkcur  = take(256 * 4);
    size_t o_cnt    = take((size_t)N * 4);
    size_t o_pos    = take((size_t)N * 4);
    size_t o_dinv   = take((size_t)N * 4);
    size_t o_srcs   = take(((size_t)E + (size_t)NB * (7 << BSH) + 64) * 4);
    size_t o_WT     = take(2 * 128 * 128 * 2);
    size_t big_sz   = (size_t)E * 8 > (size_t)N * 256 ? (size_t)E * 8 : (size_t)N * 256;
    size_t o_big    = take(big_sz);
    (void)ws_size;

    int*      bhist  = (int*)(ws + o_bhist);
    int*      bkbase = (int*)(ws + o_bkbase);
    int*      bkcur  = (int*)(ws + o_bkcur);
    int*      cnt    = (int*)(ws + o_cnt);
    int*      pos    = (int*)(ws + o_pos);
    float*    dinv   = (float*)(ws + o_dinv);
    int*      srcs   = (int*)(ws + o_srcs);
    ushort_t* WT     = (ushort_t*)(ws + o_WT);
    int*      bs     = (int*)(ws + o_big);           // CSR-build phase only
    int*      bd     = (int*)(ws + o_big) + E;
    ushort_t* xt2    = (ushort_t*)(ws + o_big);      // layer 2 slabs (bs/bd dead)
    // d_out split: xt1 slabs (lower N*256 B) + hbf slabs (upper N*256 B);
    // both dead before agg2 overwrites d_out with the final f32 output.
    ushort_t* xt1    = (ushort_t*)d_out;
    ushort_t* hbf    = (ushort_t*)d_out + (size_t)N * 128;

    hipMemsetAsync(d_ws, 0, zero_end, stream);

    int nch = (E + 4095) / 4096;
    int gG  = (N + 63) / 64;
    int gA  = 8 * ((N + 15) / 16);
    unsigned Nu = (unsigned)N;

    // hist (LDS only) + W transpose
    k_histT<<<nch + 2, 256, 0, stream>>>(ei, E, Nu, bhist, BSH, NB, nch, W1, W2, WT);
    k_scanb<<<1, 256, 0, stream>>>(bhist, NB, bkbase, bkcur);
    // bucket scatter || GEMM1 unscaled (xt1 slabs = bf16(x @ W1)) — independent
    k_bg<<<nch + gG, 256, 0, stream>>>(ei, E, Nu, bkcur, bs, bd, BSH, NB, nch,
                                       x, WT, xt1, N);
    // count + assign + fill (LDS; computes cnt/dinv/pos/srcs)
    k_caf<<<NB, 256, 0, stream>>>(bs, bd, bkbase, bkcur, N, BSH, pos, cnt, dinv, srcs);

    // layer 1: hbf slabs = bf16(agg_weighted(xt1) + b1)
    k_agg<true, true><<<gA, 256, 0, stream>>>(xt1, b1, hbf, pos, cnt, dinv, srcs, N);
    // layer 2: xt2 slabs = bf16(dinv * (hbf @ W2)); out = agg(xt2) + b2 (f32)
    k_gemm2<<<gG, 256, 0, stream>>>(hbf, WT + 16384, xt2, dinv, N);
    k_agg<false, false><<<gA, 256, 0, stream>>>(xt2, b2, out, pos, cnt, dinv, srcs, N);
}

// Round 11
// 335.096 us; speedup vs baseline: 1.7367x; 1.7367x over previous
//
#include <hip/hip_runtime.h>

typedef unsigned short ushort_t;
typedef __attribute__((ext_vector_type(8))) short short8;
typedef __attribute__((ext_vector_type(8))) unsigned short us8v;
typedef __attribute__((ext_vector_type(4))) float f32x4;

__device__ __forceinline__ float b2f(unsigned short u) {
    union { unsigned int i; float f; } v; v.i = ((unsigned int)u) << 16; return v.f;
}
__device__ __forceinline__ unsigned short f2b(float f) {
    union { float f; unsigned int i; } v; v.f = f;
    unsigned int r = (v.i + 0x7FFF + ((v.i >> 16) & 1)) >> 16;
    return (unsigned short)r;
}

// int64 path: low words carry the value (nonneg < 2^31); 8B coalesced loads
__device__ __forceinline__ void load_edge(const int* __restrict__ ei, int e, int E,
                                          int is64, int& s, int& d) {
    if (is64) {
        const long long* el = (const long long*)ei;
        s = (int)el[e]; d = (int)el[E + e];
    } else {
        s = ei[e]; d = ei[E + e];
    }
}

// detection: odd int32 words of first 512 entries all zero => int64
__device__ __forceinline__ int detect64(const int* __restrict__ ei, int t) {
    int z = 0;
    for (int i = t; i < 512; i += 256) z |= ei[2 * i + 1];
    return (__syncthreads_or(z) == 0);
}

// ---- bucket hist (blocks < nch) + W transpose (2 blocks) + last-block scan
// Last-block pattern does ONLY the 256-wide bhist scan (R8 lesson: no O(N)
// serial work, no per-edge global atomics).
__global__ __launch_bounds__(256) void k_histT(const int* __restrict__ ei, int E,
                                               unsigned N, int* __restrict__ bhist,
                                               int BSH, int NB, int nch,
                                               const float* __restrict__ W1,
                                               const float* __restrict__ W2,
                                               ushort_t* __restrict__ WT,
                                               int* __restrict__ done,
                                               int* __restrict__ bkbase,
                                               int* __restrict__ bkcur) {
    __shared__ int lh[256];
    __shared__ int lastFlag;
    int t = threadIdx.x;
    int b = blockIdx.x;
    if (b >= nch) {
        const float* src = (b == nch) ? W1 : W2;
        ushort_t* dst = WT + (b - nch) * 16384;
        for (int i = t; i < 16384; i += 256) {
            int n = i >> 7, k = i & 127;
            dst[i] = f2b(src[k * 128 + n]);   // WT[n][k] = W[k][n]
        }
    } else {
        for (int q = t; q < NB; q += 256) lh[q] = 0;
        int is64 = detect64(ei, t);   // includes __syncthreads
        int e0 = b * 4096;
        #pragma unroll
        for (int i = 0; i < 16; ++i) {
            int e = e0 + i * 256 + t;
            if (e < E) {
                int d = is64 ? (int)((const long long*)ei)[E + e] : ei[E + e];
                if ((unsigned)d < N) atomicAdd(&lh[d >> BSH], 1);
            }
        }
        __syncthreads();
        for (int q = t; q < NB; q += 256) {
            int v = lh[q]; if (v) atomicAdd(&bhist[q], v);
        }
    }
    __threadfence();
    if (t == 0) lastFlag = (atomicAdd(done, 1) == (int)gridDim.x - 1);
    __syncthreads();
    if (lastFlag) {
        __threadfence();
        int v0 = (t < NB) ? atomicAdd(&bhist[t], 0) : 0;   // coherent read
        lh[t] = v0;
        for (int o = 1; o < 256; o <<= 1) {
            __syncthreads();
            int v = (t >= o) ? lh[t - o] : 0;
            __syncthreads();
            lh[t] += v;
        }
        __syncthreads();
        if (t < NB) { int ex = lh[t] - v0; bkbase[t] = ex; bkcur[t] = ex; }
    }
}

// ---- fused: bucket scatter (blocks < nch) || GEMM1 unscaled (rest) ------
__global__ __launch_bounds__(256) void k_bg(const int* __restrict__ ei, int E,
                                            unsigned N, int* __restrict__ bkcur,
                                            int* __restrict__ bs, int* __restrict__ bd,
                                            int BSH, int NB, int nch,
                                            const float* __restrict__ x,
                                            const ushort_t* __restrict__ WT,
                                            ushort_t* __restrict__ xt, int M) {
    __shared__ __align__(16) int smem[13056];   // 52224 B union
    int t = threadIdx.x;
    int b = blockIdx.x;

    if (b < nch) {
        // ---------------- bucket scatter (proven pattern) ----------------
        int* lss = smem;             // [4096]
        int* ldd = smem + 4096;      // [4096]
        int* lhist = smem + 8192;    // [256]
        int* lcur = smem + 8448;     // [256]
        int e0 = b * 4096;
        for (int q = t; q < NB; q += 256) lhist[q] = 0;
        int is64 = detect64(ei, t);
        #pragma unroll
        for (int i = 0; i < 16; ++i) {
            int idx = i * 256 + t, e = e0 + idx;
            int s = -1, d = -1;
            if (e < E) {
                load_edge(ei, e, E, is64, s, d);
                if (!((unsigned)s < N && (unsigned)d < N)) d = -1;
            }
            lss[idx] = s; ldd[idx] = d;
            if (d >= 0) atomicAdd(&lhist[d >> BSH], 1);
        }
        __syncthreads();
        for (int q = t; q < NB; q += 256) {
            int v = lhist[q];
            lcur[q] = v ? atomicAdd(&bkcur[q], v) : 0;
        }
        __syncthreads();
        #pragma unroll
        for (int i = 0; i < 16; ++i) {
            int idx = i * 256 + t;
            int d = ldd[idx];
            if (d >= 0) {
                int p = atomicAdd(&lcur[d >> BSH], 1);
                bs[p] = lss[idx]; bd[p] = d;
            }
        }
    } else {
        // ---------------- GEMM1: xt = bf16(x @ W1), unscaled -------------
        ushort_t* sA = (ushort_t*)smem;            // 64*136
        ushort_t* sW = (ushort_t*)smem + 8704;     // 128*136
        int row0 = (b - nch) * 64;
        #pragma unroll
        for (int it = 0; it < 8; ++it) {
            int flat = (it * 256 + t) * 8;
            int n = flat >> 7, k = flat & 127;
            uint4 v = *(const uint4*)(WT + flat);
            *(uint4*)(&sW[n * 136 + k]) = v;
        }
        #pragma unroll
        for (int it = 0; it < 4; ++it) {
            int flat = (it * 256 + t) * 8;
            int r = flat >> 7, cc = flat & 127;
            int row = row0 + r; if (row > M - 1) row = M - 1;
            const float* p = x + (size_t)row * 128 + cc;
            float4 f0 = *(const float4*)p;
            float4 f1 = *(const float4*)(p + 4);
            ushort_t tmp[8] __attribute__((aligned(16)));
            tmp[0] = f2b(f0.x); tmp[1] = f2b(f0.y); tmp[2] = f2b(f0.z); tmp[3] = f2b(f0.w);
            tmp[4] = f2b(f1.x); tmp[5] = f2b(f1.y); tmp[6] = f2b(f1.z); tmp[7] = f2b(f1.w);
            *(uint4*)(&sA[r * 136 + cc]) = *(const uint4*)tmp;
        }
        __syncthreads();
        int w = t >> 6, lane = t & 63;
        int m = lane & 15, quad = lane >> 4;
        f32x4 acc[8] = {};
        #pragma unroll
        for (int k0 = 0; k0 < 128; k0 += 32) {
            short8 af = *(const short8*)(&sA[(w * 16 + m) * 136 + k0 + quad * 8]);
            #pragma unroll
            for (int tt = 0; tt < 8; ++tt) {
                short8 bf = *(const short8*)(&sW[(tt * 16 + m) * 136 + k0 + quad * 8]);
                acc[tt] = __builtin_amdgcn_mfma_f32_16x16x32_bf16(af, bf, acc[tt], 0, 0, 0);
            }
        }
        #pragma unroll
        for (int r = 0; r < 4; ++r) {
            int row = row0 + w * 16 + quad * 4 + r;
            if (row < M) {
                #pragma unroll
                for (int tt = 0; tt < 8; ++tt)
                    xt[(size_t)row * 128 + tt * 16 + m] = f2b(acc[tt][r]);
            }
        }
    }
}

// ---- fused count + padded-scan/assign + fill, all bucket-local ----------
// Lists padded to multiples of 4 (issue-bound agg: minimize pad gathers).
// cnt stores TRUE count; pads point at the destination itself.
// Bucket b's srcs segment starts at bkbase[b] + b*(3<<BSH).
__global__ __launch_bounds__(256) void k_caf(const int* __restrict__ bs,
                                             const int* __restrict__ bd,
                                             const int* __restrict__ bkbase,
                                             const int* __restrict__ bkcur,
                                             int N, int BSH,
                                             int* __restrict__ pos,
                                             int* __restrict__ cnt,
                                             float* __restrict__ dinv,
                                             int* __restrict__ srcs) {
    __shared__ int lc[512];   // counts, then fill cursors
    __shared__ int sc[512];   // padded-count inclusive scan
    int b = blockIdx.x, t = threadIdx.x;
    int nbase = b << BSH;
    int nn = min(1 << BSH, N - nbase);
    int segbase = bkbase[b] + b * (3 << BSH);

    lc[t] = 0; lc[t + 256] = 0;
    __syncthreads();
    int s0 = bkbase[b], s1 = bkcur[b];
    for (int i = s0 + t; i < s1; i += 256) atomicAdd(&lc[bd[i] - nbase], 1);
    __syncthreads();

    int c0 = (t < nn) ? lc[t] : 0;
    int c1 = (t + 256 < nn) ? lc[t + 256] : 0;
    int p0 = (c0 + 3) & ~3;                // pad each list to multiple of 4
    int p1 = (c1 + 3) & ~3;
    sc[t] = p0; sc[t + 256] = p1;
    __syncthreads();
    for (int o = 1; o < 512; o <<= 1) {
        int v0 = (t >= o) ? sc[t - o] : 0;
        int v1 = (t + 256 >= o) ? sc[t + 256 - o] : 0;
        __syncthreads();
        sc[t] += v0; sc[t + 256] += v1;
        __syncthreads();
    }
    if (t < nn) {
        int st = segbase + sc[t] - p0;
        pos[nbase + t] = st;
        cnt[nbase + t] = c0;                       // TRUE count
        dinv[nbase + t] = rsqrtf((float)c0 + 1.0f);
        for (int q = c0; q < p0; ++q) srcs[st + q] = nbase + t;  // self pads
        lc[t] = st;
    }
    if (t + 256 < nn) {
        int st = segbase + sc[t + 256] - p1;
        pos[nbase + t + 256] = st;
        cnt[nbase + t + 256] = c1;
        dinv[nbase + t + 256] = rsqrtf((float)c1 + 1.0f);
        for (int q = c1; q < p1; ++q) srcs[st + q] = nbase + t + 256;
        lc[t + 256] = st;
    }
    __syncthreads();
    for (int i = s0 + t; i < s1; i += 256) {
        int d = bd[i];
        int p = atomicAdd(&lc[d - nbase], 1);
        srcs[p] = bs[i];
    }
}

// ---- GEMM (standalone, layer 2): C = bf16(dinv * (A_bf16 @ W)) ----------
__global__ __launch_bounds__(256) void k_gemm2(const ushort_t* __restrict__ A,
                                               const ushort_t* __restrict__ WT,
                                               ushort_t* __restrict__ C,
                                               const float* __restrict__ dinv, int M) {
    __shared__ __align__(16) ushort_t sA[64 * 136];
    __shared__ __align__(16) ushort_t sW[128 * 136];
    int t = threadIdx.x;
    int row0 = blockIdx.x * 64;
    #pragma unroll
    for (int it = 0; it < 8; ++it) {
        int flat = (it * 256 + t) * 8;
        int n = flat >> 7, k = flat & 127;
        uint4 v = *(const uint4*)(WT + flat);
        *(uint4*)(&sW[n * 136 + k]) = v;
    }
    #pragma unroll
    for (int it = 0; it < 4; ++it) {
        int flat = (it * 256 + t) * 8;
        int r = flat >> 7, cc = flat & 127;
        int row = row0 + r; if (row > M - 1) row = M - 1;
        us8v v = *(const us8v*)(A + ((size_t)row << 7) + cc);
        *(us8v*)(&sA[r * 136 + cc]) = v;
    }
    __syncthreads();
    int w = t >> 6, lane = t & 63;
    int m = lane & 15, quad = lane >> 4;
    f32x4 acc[8] = {};
    #pragma unroll
    for (int k0 = 0; k0 < 128; k0 += 32) {
        short8 af = *(const short8*)(&sA[(w * 16 + m) * 136 + k0 + quad * 8]);
        #pragma unroll
        for (int tt = 0; tt < 8; ++tt) {
            short8 bf = *(const short8*)(&sW[(tt * 16 + m) * 136 + k0 + quad * 8]);
            acc[tt] = __builtin_amdgcn_mfma_f32_16x16x32_bf16(af, bf, acc[tt], 0, 0, 0);
        }
    }
    #pragma unroll
    for (int r = 0; r < 4; ++r) {
        int row = row0 + w * 16 + quad * 4 + r;
        if (row < M) {
            float dd = dinv[row];
            #pragma unroll
            for (int tt = 0; tt < 8; ++tt)
                C[(size_t)row * 128 + tt * 16 + m] = f2b(dd * acc[tt][r]);
        }
    }
}

// ---- Aggregation (row-major xt, 4 slots x 16 lanes x us8) ---------------
// Lists padded to 4 with SELF entries (k pads), cnt = TRUE count.
// WEI=true  (layer 1): o = dd*sum(dinv[s]*xt[s]) + (1-k)*dd*dd*xt[d] + b
// WEI=false (layer 2): o = dd*(sum + (1-k)*xt[d]) + b
template <bool OBF, bool WEI>
__global__ __launch_bounds__(256) void k_agg(const ushort_t* __restrict__ xt,
                                             const float* __restrict__ bias,
                                             void* __restrict__ outp,
                                             const int* __restrict__ pos,
                                             const int* __restrict__ cnts,
                                             const float* __restrict__ dinv,
                                             const int* __restrict__ srcs, int N) {
    int lane = threadIdx.x & 63;
    int slot = lane >> 4, j = lane & 15;
    int d = (blockIdx.x << 2) + (threadIdx.x >> 6);
    if (d >= N) return;
    int c = cnts[d];                        // true count
    int cn = (c + 3) & ~3;                  // padded loop bound (multiple of 4)
    float kpad = (float)(cn - c);
    int start = pos[d];
    float dd = dinv[d];
    float selfc = WEI ? (1.f - kpad) * dd * dd : (1.f - kpad) * dd;
    us8v vs = *(const us8v*)(xt + ((size_t)d << 7) + (j << 3));
    float4 bb0 = *(const float4*)(bias + (j << 3));
    float4 bb1 = *(const float4*)(bias + (j << 3) + 4);

    float a0 = 0.f, a1 = 0.f, a2 = 0.f, a3 = 0.f;
    float a4 = 0.f, a5 = 0.f, a6 = 0.f, a7 = 0.f;

    for (int base = 0; base < cn; base += 64) {
        int n = cn - base; if (n > 64) n = 64;   // multiple of 4
        int sv = 0; float wv = 1.f;
        if (lane < n) {
            sv = srcs[start + base + lane];
            if (WEI) wv = dinv[sv];
        }
        int n8 = n & ~7;                     // 8-aligned part (2-deep pipeline)
        if (n8) {
            int s0 = __shfl(sv, slot);
            int s1 = __shfl(sv, 4 + slot);
            float w0 = WEI ? __shfl(wv, slot) : 1.f;
            float w1 = WEI ? __shfl(wv, 4 + slot) : 1.f;
            us8v v0 = *(const us8v*)(xt + ((size_t)s0 << 7) + (j << 3));
            us8v v1 = *(const us8v*)(xt + ((size_t)s1 << 7) + (j << 3));
            for (int cc = 8; cc < n8; cc += 8) {
                int t0 = __shfl(sv, cc + slot);
                int t1 = __shfl(sv, cc + 4 + slot);
                float u0 = WEI ? __shfl(wv, cc + slot) : 1.f;
                float u1 = WEI ? __shfl(wv, cc + 4 + slot) : 1.f;
                us8v m0 = *(const us8v*)(xt + ((size_t)t0 << 7) + (j << 3));
                us8v m1 = *(const us8v*)(xt + ((size_t)t1 << 7) + (j << 3));
                a0 += w0 * b2f(v0[0]); a1 += w0 * b2f(v0[1]);
                a2 += w0 * b2f(v0[2]); a3 += w0 * b2f(v0[3]);
                a4 += w0 * b2f(v0[4]); a5 += w0 * b2f(v0[5]);
                a6 += w0 * b2f(v0[6]); a7 += w0 * b2f(v0[7]);
                a0 += w1 * b2f(v1[0]); a1 += w1 * b2f(v1[1]);
                a2 += w1 * b2f(v1[2]); a3 += w1 * b2f(v1[3]);
                a4 += w1 * b2f(v1[4]); a5 += w1 * b2f(v1[5]);
                a6 += w1 * b2f(v1[6]); a7 += w1 * b2f(v1[7]);
                v0 = m0; v1 = m1; w0 = u0; w1 = u1;
            }
            a0 += w0 * b2f(v0[0]); a1 += w0 * b2f(v0[1]);
            a2 += w0 * b2f(v0[2]); a3 += w0 * b2f(v0[3]);
            a4 += w0 * b2f(v0[4]); a5 += w0 * b2f(v0[5]);
            a6 += w0 * b2f(v0[6]); a7 += w0 * b2f(v0[7]);
            a0 += w1 * b2f(v1[0]); a1 += w1 * b2f(v1[1]);
            a2 += w1 * b2f(v1[2]); a3 += w1 * b2f(v1[3]);
            a4 += w1 * b2f(v1[4]); a5 += w1 * b2f(v1[5]);
            a6 += w1 * b2f(v1[6]); a7 += w1 * b2f(v1[7]);
        }
        if (n & 4) {                         // 4-edge tail (one load)
            int s = __shfl(sv, n8 + slot);
            float w = WEI ? __shfl(wv, n8 + slot) : 1.f;
            us8v v = *(const us8v*)(xt + ((size_t)s << 7) + (j << 3));
            a0 += w * b2f(v[0]); a1 += w * b2f(v[1]);
            a2 += w * b2f(v[2]); a3 += w * b2f(v[3]);
            a4 += w * b2f(v[4]); a5 += w * b2f(v[5]);
            a6 += w * b2f(v[6]); a7 += w * b2f(v[7]);
        }
    }
    // reduce the 4 edge-slots: lanes (j, j+16, j+32, j+48) hold same features
    a0 += __shfl_xor(a0, 32); a1 += __shfl_xor(a1, 32);
    a2 += __shfl_xor(a2, 32); a3 += __shfl_xor(a3, 32);
    a4 += __shfl_xor(a4, 32); a5 += __shfl_xor(a5, 32);
    a6 += __shfl_xor(a6, 32); a7 += __shfl_xor(a7, 32);
    a0 += __shfl_xor(a0, 16); a1 += __shfl_xor(a1, 16);
    a2 += __shfl_xor(a2, 16); a3 += __shfl_xor(a3, 16);
    a4 += __shfl_xor(a4, 16); a5 += __shfl_xor(a5, 16);
    a6 += __shfl_xor(a6, 16); a7 += __shfl_xor(a7, 16);

    if (slot == 0) {
        float o0 = dd * a0 + selfc * b2f(vs[0]) + bb0.x;
        float o1 = dd * a1 + selfc * b2f(vs[1]) + bb0.y;
        float o2 = dd * a2 + selfc * b2f(vs[2]) + bb0.z;
        float o3 = dd * a3 + selfc * b2f(vs[3]) + bb0.w;
        float o4 = dd * a4 + selfc * b2f(vs[4]) + bb1.x;
        float o5 = dd * a5 + selfc * b2f(vs[5]) + bb1.y;
        float o6 = dd * a6 + selfc * b2f(vs[6]) + bb1.z;
        float o7 = dd * a7 + selfc * b2f(vs[7]) + bb1.w;
        if (OBF) {
            ushort_t tmp[8] __attribute__((aligned(16)));
            tmp[0] = f2b(o0); tmp[1] = f2b(o1); tmp[2] = f2b(o2); tmp[3] = f2b(o3);
            tmp[4] = f2b(o4); tmp[5] = f2b(o5); tmp[6] = f2b(o6); tmp[7] = f2b(o7);
            *(us8v*)((ushort_t*)outp + ((size_t)d << 7) + (j << 3)) = *(const us8v*)tmp;
        } else {
            float4 q0 = { o0, o1, o2, o3 };
            float4 q1 = { o4, o5, o6, o7 };
            float4* po = (float4*)((float*)outp + ((size_t)d << 7) + (j << 3));
            po[0] = q0; po[1] = q1;
        }
    }
}

// ---- launch -------------------------------------------------------------

extern "C" void kernel_launch(void* const* d_in, const int* in_sizes, int n_in,
                              void* d_out, int out_size, void* d_ws, size_t ws_size,
                              hipStream_t stream) {
    const float* x  = (const float*)d_in[0];   // [N,128] f32
    const int*   ei = (const int*)d_in[1];     // [2,E] int32/int64 (detected)
    const float* W1 = (const float*)d_in[2];   // [128,128] f32
    const float* b1 = (const float*)d_in[3];   // [128] f32
    const float* W2 = (const float*)d_in[4];
    const float* b2 = (const float*)d_in[5];
    float* out = (float*)d_out;                // [N,128] f32

    const int N = in_sizes[0] / 128;
    const int E = in_sizes[1] / 2;

    // bucket size 2^BSH nodes, NB <= 256 buckets (N=100000 -> BSH=9, NB=196)
    int BSH = 9;
    int NB = (N + (1 << BSH) - 1) >> BSH;
    while (NB > 256) { BSH++; NB = (N + (1 << BSH) - 1) >> BSH; }

    char* ws = (char*)d_ws;
    size_t o = 0;
    auto take = [&](size_t bytes) { size_t r = o; o = (o + bytes + 255) & ~(size_t)255; return r; };
    size_t o_bhist  = take(256 * 4);
    size_t o_done   = take(4);
    size_t zero_end = o;                  // memset [0, zero_end): bhist + done
    size_t o_bkbase = take(256 * 4);
    size_t o_bkcur  = take(256 * 4);
    size_t o_cnt    = take((size_t)N * 4);
    size_t o_pos    = take((size_t)N * 4);
    size_t o_dinv   = take((size_t)N * 4);
    size_t o_srcs   = take(((size_t)E + (size_t)NB * (3 << BSH) + 64) * 4);
    size_t o_WT     = take(2 * 128 * 128 * 2);
    size_t big_sz   = (size_t)E * 8 > (size_t)N * 256 ? (size_t)E * 8 : (size_t)N * 256;
    size_t o_big    = take(big_sz);
    (void)ws_size;

    int*      bhist  = (int*)(ws + o_bhist);
    int*      done   = (int*)(ws + o_done);
    int*      bkbase = (int*)(ws + o_bkbase);
    int*      bkcur  = (int*)(ws + o_bkcur);
    int*      cnt    = (int*)(ws + o_cnt);
    int*      pos    = (int*)(ws + o_pos);
    float*    dinv   = (float*)(ws + o_dinv);
    int*      srcs   = (int*)(ws + o_srcs);
    ushort_t* WT     = (ushort_t*)(ws + o_WT);
    int*      bs     = (int*)(ws + o_big);           // CSR-build phase only
    int*      bd     = (int*)(ws + o_big) + E;
    ushort_t* xt2    = (ushort_t*)(ws + o_big);      // layer 2 (bs/bd dead)
    // d_out split: xt1 (lower N*256 B) + hbf (upper N*256 B); both dead
    // before agg2 overwrites d_out with the final f32 output.
    ushort_t* xt1    = (ushort_t*)d_out;
    ushort_t* hbf    = (ushort_t*)d_out + (size_t)N * 128;

    hipMemsetAsync(d_ws, 0, zero_end, stream);

    int nch = (E + 4095) / 4096;
    int gG  = (N + 63) / 64;
    int gA  = (N + 3) / 4;
    unsigned Nu = (unsigned)N;

    // hist (LDS only) + W transpose + last-block bhist scan
    k_histT<<<nch + 2, 256, 0, stream>>>(ei, E, Nu, bhist, BSH, NB, nch,
                                         W1, W2, WT, done, bkbase, bkcur);
    // bucket scatter || GEMM1 unscaled (xt1 = bf16(x @ W1)) — independent
    k_bg<<<nch + gG, 256, 0, stream>>>(ei, E, Nu, bkcur, bs, bd, BSH, NB, nch,
                                       x, WT, xt1, N);
    // count + assign + fill (LDS; computes cnt/dinv/pos/srcs; pad-4)
    k_caf<<<NB, 256, 0, stream>>>(bs, bd, bkbase, bkcur, N, BSH, pos, cnt, dinv, srcs);

    // layer 1: hbf = bf16(agg_weighted(xt1) + b1)
    k_agg<true, true><<<gA, 256, 0, stream>>>(xt1, b1, hbf, pos, cnt, dinv, srcs, N);
    // layer 2: xt2 = bf16(dinv * (hbf @ W2)); out = agg(xt2) + b2 (f32)
    k_gemm2<<<gG, 256, 0, stream>>>(hbf, WT + 16384, xt2, dinv, N);
    k_agg<false, false><<<gA, 256, 0, stream>>>(xt2, b2, out, pos, cnt, dinv, srcs, N);
}

// Round 12
// 318.661 us; speedup vs baseline: 1.8262x; 1.0516x over previous
//
#include <hip/hip_runtime.h>

typedef unsigned short ushort_t;
typedef __attribute__((ext_vector_type(8))) short short8;
typedef __attribute__((ext_vector_type(8))) unsigned short us8v;
typedef __attribute__((ext_vector_type(4))) float f32x4;

__device__ __forceinline__ float b2f(unsigned short u) {
    union { unsigned int i; float f; } v; v.i = ((unsigned int)u) << 16; return v.f;
}
__device__ __forceinline__ unsigned short f2b(float f) {
    union { float f; unsigned int i; } v; v.f = f;
    unsigned int r = (v.i + 0x7FFF + ((v.i >> 16) & 1)) >> 16;
    return (unsigned short)r;
}

// int64 path: low words carry the value (nonneg < 2^31); 8B coalesced loads
__device__ __forceinline__ void load_edge(const int* __restrict__ ei, int e, int E,
                                          int is64, int& s, int& d) {
    if (is64) {
        const long long* el = (const long long*)ei;
        s = (int)el[e]; d = (int)el[E + e];
    } else {
        s = ei[e]; d = ei[E + e];
    }
}

// detection: odd int32 words of first 512 entries all zero => int64
__device__ __forceinline__ int detect64(const int* __restrict__ ei, int t) {
    int z = 0;
    for (int i = t; i < 512; i += 256) z |= ei[2 * i + 1];
    return (__syncthreads_or(z) == 0);
}

// ---- shared GEMM1 block body: xt[row0..row0+63] = bf16(x @ W1) ----------
__device__ __forceinline__ void gemm1_block(const float* __restrict__ x,
                                            const ushort_t* __restrict__ WT,
                                            ushort_t* __restrict__ xt, int M,
                                            int row0, int* smem, int t) {
    ushort_t* sA = (ushort_t*)smem;            // 64*136
    ushort_t* sW = (ushort_t*)smem + 8704;     // 128*136
    #pragma unroll
    for (int it = 0; it < 8; ++it) {
        int flat = (it * 256 + t) * 8;
        int n = flat >> 7, k = flat & 127;
        uint4 v = *(const uint4*)(WT + flat);
        *(uint4*)(&sW[n * 136 + k]) = v;
    }
    #pragma unroll
    for (int it = 0; it < 4; ++it) {
        int flat = (it * 256 + t) * 8;
        int r = flat >> 7, cc = flat & 127;
        int row = row0 + r; if (row > M - 1) row = M - 1;
        const float* p = x + (size_t)row * 128 + cc;
        float4 f0 = *(const float4*)p;
        float4 f1 = *(const float4*)(p + 4);
        ushort_t tmp[8] __attribute__((aligned(16)));
        tmp[0] = f2b(f0.x); tmp[1] = f2b(f0.y); tmp[2] = f2b(f0.z); tmp[3] = f2b(f0.w);
        tmp[4] = f2b(f1.x); tmp[5] = f2b(f1.y); tmp[6] = f2b(f1.z); tmp[7] = f2b(f1.w);
        *(uint4*)(&sA[r * 136 + cc]) = *(const uint4*)tmp;
    }
    __syncthreads();
    int w = t >> 6, lane = t & 63;
    int m = lane & 15, quad = lane >> 4;
    f32x4 acc[8] = {};
    #pragma unroll
    for (int k0 = 0; k0 < 128; k0 += 32) {
        short8 af = *(const short8*)(&sA[(w * 16 + m) * 136 + k0 + quad * 8]);
        #pragma unroll
        for (int tt = 0; tt < 8; ++tt) {
            short8 bf = *(const short8*)(&sW[(tt * 16 + m) * 136 + k0 + quad * 8]);
            acc[tt] = __builtin_amdgcn_mfma_f32_16x16x32_bf16(af, bf, acc[tt], 0, 0, 0);
        }
    }
    #pragma unroll
    for (int r = 0; r < 4; ++r) {
        int row = row0 + w * 16 + quad * 4 + r;
        if (row < M) {
            #pragma unroll
            for (int tt = 0; tt < 8; ++tt)
                xt[(size_t)row * 128 + tt * 16 + m] = f2b(acc[tt][r]);
        }
    }
}

// ---- bucket histogram (blocks < nch) + W transpose (2 extra blocks) -----
__global__ __launch_bounds__(256) void k_histT(const int* __restrict__ ei, int E,
                                               unsigned N, int* __restrict__ bhist,
                                               int BSH, int NB, int nch,
                                               const float* __restrict__ W1,
                                               const float* __restrict__ W2,
                                               ushort_t* __restrict__ WT) {
    __shared__ int lh[256];
    int t = threadIdx.x;
    int b = blockIdx.x;
    if (b >= nch) {
        const float* src = (b == nch) ? W1 : W2;
        ushort_t* dst = WT + (b - nch) * 16384;
        for (int i = t; i < 16384; i += 256) {
            int n = i >> 7, k = i & 127;
            dst[i] = f2b(src[k * 128 + n]);   // WT[n][k] = W[k][n]
        }
        return;
    }
    for (int q = t; q < NB; q += 256) lh[q] = 0;
    int is64 = detect64(ei, t);   // includes __syncthreads
    int e0 = b * 4096;
    #pragma unroll
    for (int i = 0; i < 16; ++i) {
        int e = e0 + i * 256 + t;
        if (e < E) {
            int d = is64 ? (int)((const long long*)ei)[E + e] : ei[E + e];
            if ((unsigned)d < N) atomicAdd(&lh[d >> BSH], 1);
        }
    }
    __syncthreads();
    for (int q = t; q < NB; q += 256) { int v = lh[q]; if (v) atomicAdd(&bhist[q], v); }
}

// ---- fused: bucket scatter (blocks < nch) || GEMM1 part A (rest) --------
// Bucket blocks compute bkbase locally (LDS scan of bhist); bkcur is a
// zero-initialized DELTA cursor -> no k_scanb dispatch needed.
__global__ __launch_bounds__(256) void k_bg(const int* __restrict__ ei, int E,
                                            unsigned N, const int* __restrict__ bhist,
                                            int* __restrict__ bkcur,
                                            int* __restrict__ bs, int* __restrict__ bd,
                                            int BSH, int NB, int nch,
                                            const float* __restrict__ x,
                                            const ushort_t* __restrict__ WT,
                                            ushort_t* __restrict__ xt, int M) {
    __shared__ __align__(16) int smem[13056];   // 52224 B union
    int t = threadIdx.x;
    int b = blockIdx.x;

    if (b < nch) {
        int* lss = smem;             // [4096]
        int* ldd = smem + 4096;      // [4096]
        int* lhist = smem + 8192;    // [256]
        int* lcur = smem + 8448;     // [256]
        int* sbk = smem + 8704;      // [256] exclusive scan of bhist
        int e0 = b * 4096;
        // local exclusive scan of bhist
        int hv = (t < NB) ? bhist[t] : 0;
        sbk[t] = hv;
        for (int o = 1; o < 256; o <<= 1) {
            __syncthreads();
            int v = (t >= o) ? sbk[t - o] : 0;
            __syncthreads();
            sbk[t] += v;
        }
        __syncthreads();
        sbk[t] -= hv;                // exclusive
        for (int q = t; q < NB; q += 256) lhist[q] = 0;
        int is64 = detect64(ei, t);  // includes __syncthreads
        #pragma unroll
        for (int i = 0; i < 16; ++i) {
            int idx = i * 256 + t, e = e0 + idx;
            int s = -1, d = -1;
            if (e < E) {
                load_edge(ei, e, E, is64, s, d);
                if (!((unsigned)s < N && (unsigned)d < N)) d = -1;
            }
            lss[idx] = s; ldd[idx] = d;
            if (d >= 0) atomicAdd(&lhist[d >> BSH], 1);
        }
        __syncthreads();
        for (int q = t; q < NB; q += 256) {
            int v = lhist[q];
            lcur[q] = v ? (sbk[q] + atomicAdd(&bkcur[q], v)) : 0;
        }
        __syncthreads();
        #pragma unroll
        for (int i = 0; i < 16; ++i) {
            int idx = i * 256 + t;
            int d = ldd[idx];
            if (d >= 0) {
                int p = atomicAdd(&lcur[d >> BSH], 1);
                bs[p] = lss[idx]; bd[p] = d;
            }
        }
    } else {
        gemm1_block(x, WT, xt, M, (b - nch) * 64, smem, t);
    }
}

// ---- fused count + padded-scan/assign + fill (blocks < NB) || GEMM1 B ---
// caf blocks compute bkbase[b] locally from bhist; s1 = bkbase[b]+bhist[b].
// Lists padded to 8 with SELF entries; cnt stores TRUE count.
// Bucket b's srcs segment starts at bkbase[b] + b*(7<<BSH).
__global__ __launch_bounds__(256) void k_caf(const int* __restrict__ bs,
                                             const int* __restrict__ bd,
                                             const int* __restrict__ bhist,
                                             int N, int BSH, int NB,
                                             int* __restrict__ pos,
                                             int* __restrict__ cnt,
                                             float* __restrict__ dinv,
                                             int* __restrict__ srcs,
                                             const float* __restrict__ x,
                                             const ushort_t* __restrict__ WT,
                                             ushort_t* __restrict__ xt, int M,
                                             int GH1) {
    __shared__ __align__(16) int smem[13056];   // union with gemm branch
    int t = threadIdx.x;
    int b = blockIdx.x;
    if (b >= NB) {
        gemm1_block(x, WT, xt, M, (GH1 + b - NB) * 64, smem, t);
        return;
    }
    int* lc = smem;          // [512] counts, then fill cursors
    int* sc = smem + 512;    // [512] scans
    __shared__ int sBase, sCnt;
    int nbase = b << BSH;
    int nn = min(1 << BSH, N - nbase);

    // local exclusive scan of bhist -> bkbase[b]
    int hv = (t < NB) ? bhist[t] : 0;
    sc[t] = hv;
    for (int o = 1; o < 256; o <<= 1) {
        __syncthreads();
        int v = (t >= o) ? sc[t - o] : 0;
        __syncthreads();
        sc[t] += v;
    }
    __syncthreads();
    if (t == b) { sBase = sc[b] - hv; sCnt = hv; }   // t==b < NB <= 256
    __syncthreads();
    int s0 = sBase, s1 = sBase + sCnt;
    int segbase = sBase + b * (7 << BSH);

    lc[t] = 0; lc[t + 256] = 0;
    __syncthreads();
    for (int i = s0 + t; i < s1; i += 256) atomicAdd(&lc[bd[i] - nbase], 1);
    __syncthreads();

    int c0 = (t < nn) ? lc[t] : 0;
    int c1 = (t + 256 < nn) ? lc[t + 256] : 0;
    int p0 = (c0 + 7) & ~7;                // pad each list to multiple of 8
    int p1 = (c1 + 7) & ~7;
    sc[t] = p0; sc[t + 256] = p1;
    __syncthreads();
    for (int o = 1; o < 512; o <<= 1) {
        int v0 = (t >= o) ? sc[t - o] : 0;
        int v1 = (t + 256 >= o) ? sc[t + 256 - o] : 0;
        __syncthreads();
        sc[t] += v0; sc[t + 256] += v1;
        __syncthreads();
    }
    if (t < nn) {
        int st = segbase + sc[t] - p0;
        pos[nbase + t] = st;
        cnt[nbase + t] = c0;                       // TRUE count
        dinv[nbase + t] = rsqrtf((float)c0 + 1.0f);
        for (int q = c0; q < p0; ++q) srcs[st + q] = nbase + t;  // self pads
        lc[t] = st;
    }
    if (t + 256 < nn) {
        int st = segbase + sc[t + 256] - p1;
        pos[nbase + t + 256] = st;
        cnt[nbase + t + 256] = c1;
        dinv[nbase + t + 256] = rsqrtf((float)c1 + 1.0f);
        for (int q = c1; q < p1; ++q) srcs[st + q] = nbase + t + 256;
        lc[t + 256] = st;
    }
    __syncthreads();
    for (int i = s0 + t; i < s1; i += 256) {
        int d = bd[i];
        int p = atomicAdd(&lc[d - nbase], 1);
        srcs[p] = bs[i];
    }
}

// ---- GEMM (standalone, layer 2): C = bf16(dinv * (A_bf16 @ W)) ----------
__global__ __launch_bounds__(256) void k_gemm2(const ushort_t* __restrict__ A,
                                               const ushort_t* __restrict__ WT,
                                               ushort_t* __restrict__ C,
                                               const float* __restrict__ dinv, int M) {
    __shared__ __align__(16) ushort_t sA[64 * 136];
    __shared__ __align__(16) ushort_t sW[128 * 136];
    int t = threadIdx.x;
    int row0 = blockIdx.x * 64;
    #pragma unroll
    for (int it = 0; it < 8; ++it) {
        int flat = (it * 256 + t) * 8;
        int n = flat >> 7, k = flat & 127;
        uint4 v = *(const uint4*)(WT + flat);
        *(uint4*)(&sW[n * 136 + k]) = v;
    }
    #pragma unroll
    for (int it = 0; it < 4; ++it) {
        int flat = (it * 256 + t) * 8;
        int r = flat >> 7, cc = flat & 127;
        int row = row0 + r; if (row > M - 1) row = M - 1;
        us8v v = *(const us8v*)(A + ((size_t)row << 7) + cc);
        *(us8v*)(&sA[r * 136 + cc]) = v;
    }
    __syncthreads();
    int w = t >> 6, lane = t & 63;
    int m = lane & 15, quad = lane >> 4;
    f32x4 acc[8] = {};
    #pragma unroll
    for (int k0 = 0; k0 < 128; k0 += 32) {
        short8 af = *(const short8*)(&sA[(w * 16 + m) * 136 + k0 + quad * 8]);
        #pragma unroll
        for (int tt = 0; tt < 8; ++tt) {
            short8 bf = *(const short8*)(&sW[(tt * 16 + m) * 136 + k0 + quad * 8]);
            acc[tt] = __builtin_amdgcn_mfma_f32_16x16x32_bf16(af, bf, acc[tt], 0, 0, 0);
        }
    }
    #pragma unroll
    for (int r = 0; r < 4; ++r) {
        int row = row0 + w * 16 + quad * 4 + r;
        if (row < M) {
            float dd = dinv[row];
            #pragma unroll
            for (int tt = 0; tt < 8; ++tt)
                C[(size_t)row * 128 + tt * 16 + m] = f2b(dd * acc[tt][r]);
        }
    }
}

// ---- Aggregation (R9-proven: pad-8, 2-deep pipeline, 4x16 us8) ----------
// WEI=true  (layer 1): o = dd*sum(dinv[s]*xt[s]) + (1-k)*dd*dd*xt[d] + b
// WEI=false (layer 2): o = dd*(sum + (1-k)*xt[d]) + b
template <bool OBF, bool WEI>
__global__ __launch_bounds__(256) void k_agg(const ushort_t* __restrict__ xt,
                                             const float* __restrict__ bias,
                                             void* __restrict__ outp,
                                             const int* __restrict__ pos,
                                             const int* __restrict__ cnts,
                                             const float* __restrict__ dinv,
                                             const int* __restrict__ srcs, int N) {
    int lane = threadIdx.x & 63;
    int slot = lane >> 4, j = lane & 15;
    int d = (blockIdx.x << 2) + (threadIdx.x >> 6);
    if (d >= N) return;
    int c = cnts[d];                        // true count
    int cn = (c + 7) & ~7;                  // padded loop bound
    float kpad = (float)(cn - c);
    int start = pos[d];
    float dd = dinv[d];
    float selfc = WEI ? (1.f - kpad) * dd * dd : (1.f - kpad) * dd;
    us8v vs = *(const us8v*)(xt + ((size_t)d << 7) + (j << 3));
    float4 bb0 = *(const float4*)(bias + (j << 3));
    float4 bb1 = *(const float4*)(bias + (j << 3) + 4);

    float a0 = 0.f, a1 = 0.f, a2 = 0.f, a3 = 0.f;
    float a4 = 0.f, a5 = 0.f, a6 = 0.f, a7 = 0.f;

    for (int base = 0; base < cn; base += 64) {
        int n = cn - base; if (n > 64) n = 64;   // multiple of 8
        int sv = 0; float wv = 1.f;
        if (lane < n) {
            sv = srcs[start + base + lane];
            if (WEI) wv = dinv[sv];
        }
        int s0 = __shfl(sv, slot);
        int s1 = __shfl(sv, 4 + slot);
        float w0 = WEI ? __shfl(wv, slot) : 1.f;
        float w1 = WEI ? __shfl(wv, 4 + slot) : 1.f;
        us8v v0 = *(const us8v*)(xt + ((size_t)s0 << 7) + (j << 3));
        us8v v1 = *(const us8v*)(xt + ((size_t)s1 << 7) + (j << 3));
        for (int cc = 8; cc < n; cc += 8) {
            int t0 = __shfl(sv, cc + slot);
            int t1 = __shfl(sv, cc + 4 + slot);
            float u0 = WEI ? __shfl(wv, cc + slot) : 1.f;
            float u1 = WEI ? __shfl(wv, cc + 4 + slot) : 1.f;
            us8v m0 = *(const us8v*)(xt + ((size_t)t0 << 7) + (j << 3));
            us8v m1 = *(const us8v*)(xt + ((size_t)t1 << 7) + (j << 3));
            a0 += w0 * b2f(v0[0]); a1 += w0 * b2f(v0[1]);
            a2 += w0 * b2f(v0[2]); a3 += w0 * b2f(v0[3]);
            a4 += w0 * b2f(v0[4]); a5 += w0 * b2f(v0[5]);
            a6 += w0 * b2f(v0[6]); a7 += w0 * b2f(v0[7]);
            a0 += w1 * b2f(v1[0]); a1 += w1 * b2f(v1[1]);
            a2 += w1 * b2f(v1[2]); a3 += w1 * b2f(v1[3]);
            a4 += w1 * b2f(v1[4]); a5 += w1 * b2f(v1[5]);
            a6 += w1 * b2f(v1[6]); a7 += w1 * b2f(v1[7]);
            v0 = m0; v1 = m1; w0 = u0; w1 = u1;
        }
        a0 += w0 * b2f(v0[0]); a1 += w0 * b2f(v0[1]);
        a2 += w0 * b2f(v0[2]); a3 += w0 * b2f(v0[3]);
        a4 += w0 * b2f(v0[4]); a5 += w0 * b2f(v0[5]);
        a6 += w0 * b2f(v0[6]); a7 += w0 * b2f(v0[7]);
        a0 += w1 * b2f(v1[0]); a1 += w1 * b2f(v1[1]);
        a2 += w1 * b2f(v1[2]); a3 += w1 * b2f(v1[3]);
        a4 += w1 * b2f(v1[4]); a5 += w1 * b2f(v1[5]);
        a6 += w1 * b2f(v1[6]); a7 += w1 * b2f(v1[7]);
    }
    a0 += __shfl_xor(a0, 32); a1 += __shfl_xor(a1, 32);
    a2 += __shfl_xor(a2, 32); a3 += __shfl_xor(a3, 32);
    a4 += __shfl_xor(a4, 32); a5 += __shfl_xor(a5, 32);
    a6 += __shfl_xor(a6, 32); a7 += __shfl_xor(a7, 32);
    a0 += __shfl_xor(a0, 16); a1 += __shfl_xor(a1, 16);
    a2 += __shfl_xor(a2, 16); a3 += __shfl_xor(a3, 16);
    a4 += __shfl_xor(a4, 16); a5 += __shfl_xor(a5, 16);
    a6 += __shfl_xor(a6, 16); a7 += __shfl_xor(a7, 16);

    if (slot == 0) {
        float o0 = dd * a0 + selfc * b2f(vs[0]) + bb0.x;
        float o1 = dd * a1 + selfc * b2f(vs[1]) + bb0.y;
        float o2 = dd * a2 + selfc * b2f(vs[2]) + bb0.z;
        float o3 = dd * a3 + selfc * b2f(vs[3]) + bb0.w;
        float o4 = dd * a4 + selfc * b2f(vs[4]) + bb1.x;
        float o5 = dd * a5 + selfc * b2f(vs[5]) + bb1.y;
        float o6 = dd * a6 + selfc * b2f(vs[6]) + bb1.z;
        float o7 = dd * a7 + selfc * b2f(vs[7]) + bb1.w;
        if (OBF) {
            ushort_t tmp[8] __attribute__((aligned(16)));
            tmp[0] = f2b(o0); tmp[1] = f2b(o1); tmp[2] = f2b(o2); tmp[3] = f2b(o3);
            tmp[4] = f2b(o4); tmp[5] = f2b(o5); tmp[6] = f2b(o6); tmp[7] = f2b(o7);
            *(us8v*)((ushort_t*)outp + ((size_t)d << 7) + (j << 3)) = *(const us8v*)tmp;
        } else {
            float4 q0 = { o0, o1, o2, o3 };
            float4 q1 = { o4, o5, o6, o7 };
            float4* po = (float4*)((float*)outp + ((size_t)d << 7) + (j << 3));
            po[0] = q0; po[1] = q1;
        }
    }
}

// ---- launch -------------------------------------------------------------

extern "C" void kernel_launch(void* const* d_in, const int* in_sizes, int n_in,
                              void* d_out, int out_size, void* d_ws, size_t ws_size,
                              hipStream_t stream) {
    const float* x  = (const float*)d_in[0];   // [N,128] f32
    const int*   ei = (const int*)d_in[1];     // [2,E] int32/int64 (detected)
    const float* W1 = (const float*)d_in[2];   // [128,128] f32
    const float* b1 = (const float*)d_in[3];   // [128] f32
    const float* W2 = (const float*)d_in[4];
    const float* b2 = (const float*)d_in[5];
    float* out = (float*)d_out;                // [N,128] f32

    const int N = in_sizes[0] / 128;
    const int E = in_sizes[1] / 2;

    // bucket size 2^BSH nodes, NB <= 256 buckets (N=100000 -> BSH=9, NB=196)
    int BSH = 9;
    int NB = (N + (1 << BSH) - 1) >> BSH;
    while (NB > 256) { BSH++; NB = (N + (1 << BSH) - 1) >> BSH; }

    char* ws = (char*)d_ws;
    size_t o = 0;
    auto take = [&](size_t bytes) { size_t r = o; o = (o + bytes + 255) & ~(size_t)255; return r; };
    size_t o_bhist  = take(256 * 4);
    size_t o_bkcur  = take(256 * 4);
    size_t zero_end = o;                  // memset: bhist + bkcur (delta cursor)
    size_t o_cnt    = take((size_t)N * 4);
    size_t o_pos    = take((size_t)N * 4);
    size_t o_dinv   = take((size_t)N * 4);
    size_t o_srcs   = take(((size_t)E + (size_t)NB * (7 << BSH) + 64) * 4);
    size_t o_WT     = take(2 * 128 * 128 * 2);
    size_t big_sz   = (size_t)E * 8 > (size_t)N * 256 ? (size_t)E * 8 : (size_t)N * 256;
    size_t o_big    = take(big_sz);
    (void)ws_size;

    int*      bhist  = (int*)(ws + o_bhist);
    int*      bkcur  = (int*)(ws + o_bkcur);
    int*      cnt    = (int*)(ws + o_cnt);
    int*      pos    = (int*)(ws + o_pos);
    float*    dinv   = (float*)(ws + o_dinv);
    int*      srcs   = (int*)(ws + o_srcs);
    ushort_t* WT     = (ushort_t*)(ws + o_WT);
    int*      bs     = (int*)(ws + o_big);           // CSR-build phase only
    int*      bd     = (int*)(ws + o_big) + E;
    ushort_t* xt2    = (ushort_t*)(ws + o_big);      // layer 2 (bs/bd dead)
    // d_out split: xt1 (lower N*256 B) + hbf (upper N*256 B); both dead
    // before agg2 overwrites d_out with the final f32 output.
    ushort_t* xt1    = (ushort_t*)d_out;
    ushort_t* hbf    = (ushort_t*)d_out + (size_t)N * 128;

    hipMemsetAsync(d_ws, 0, zero_end, stream);

    int nch = (E + 4095) / 4096;
    int gG  = (N + 63) / 64;
    int GH1 = (gG + 1) / 2;                // gemm1 rows in k_bg
    int GH2 = gG - GH1;                    // gemm1 rows in k_caf dispatch
    int gA  = (N + 3) / 4;
    unsigned Nu = (unsigned)N;

    // hist (LDS only) + W transpose
    k_histT<<<nch + 2, 256, 0, stream>>>(ei, E, Nu, bhist, BSH, NB, nch, W1, W2, WT);
    // bucket scatter (in-block bhist scan, delta cursor) || GEMM1 part A
    k_bg<<<nch + GH1, 256, 0, stream>>>(ei, E, Nu, bhist, bkcur, bs, bd, BSH, NB,
                                        nch, x, WT, xt1, N);
    // count+assign+fill || GEMM1 part B (fills idle CUs)
    k_caf<<<NB + GH2, 256, 0, stream>>>(bs, bd, bhist, N, BSH, NB, pos, cnt, dinv,
                                        srcs, x, WT, xt1, N, GH1);

    // layer 1: hbf = bf16(agg_weighted(xt1) + b1)
    k_agg<true, true><<<gA, 256, 0, stream>>>(xt1, b1, hbf, pos, cnt, dinv, srcs, N);
    // layer 2: xt2 = bf16(dinv * (hbf @ W2)); out = agg(xt2) + b2 (f32)
    k_gemm2<<<gG, 256, 0, stream>>>(hbf, WT + 16384, xt2, dinv, N);
    k_agg<false, false><<<gA, 256, 0, stream>>>(xt2, b2, out, pos, cnt, dinv, srcs, N);
}

// Round 13
// 303.448 us; speedup vs baseline: 1.9178x; 1.0501x over previous
//
#include <hip/hip_runtime.h>

typedef unsigned short ushort_t;
typedef __attribute__((ext_vector_type(8))) short short8;
typedef __attribute__((ext_vector_type(8))) unsigned short us8v;
typedef __attribute__((ext_vector_type(4))) float f32x4;

__device__ __forceinline__ float b2f(unsigned short u) {
    union { unsigned int i; float f; } v; v.i = ((unsigned int)u) << 16; return v.f;
}
__device__ __forceinline__ unsigned short f2b(float f) {
    union { float f; unsigned int i; } v; v.f = f;
    unsigned int r = (v.i + 0x7FFF + ((v.i >> 16) & 1)) >> 16;
    return (unsigned short)r;
}

// int64 path: low words carry the value (nonneg < 2^31); 8B coalesced loads
__device__ __forceinline__ void load_edge(const int* __restrict__ ei, int e, int E,
                                          int is64, int& s, int& d) {
    if (is64) {
        const long long* el = (const long long*)ei;
        s = (int)el[e]; d = (int)el[E + e];
    } else {
        s = ei[e]; d = ei[E + e];
    }
}

// detection: odd int32 words of first 512 entries all zero => int64
__device__ __forceinline__ int detect64(const int* __restrict__ ei, int t) {
    int z = 0;
    for (int i = t; i < 512; i += 256) z |= ei[2 * i + 1];
    return (__syncthreads_or(z) == 0);
}

// ---- shared GEMM1 block body: xt[row0..row0+63] = bf16(x @ W1) ----------
__device__ __forceinline__ void gemm1_block(const float* __restrict__ x,
                                            const ushort_t* __restrict__ WT,
                                            ushort_t* __restrict__ xt, int M,
                                            int row0, int* smem, int t) {
    ushort_t* sA = (ushort_t*)smem;            // 64*136
    ushort_t* sW = (ushort_t*)smem + 8704;     // 128*136
    #pragma unroll
    for (int it = 0; it < 8; ++it) {
        int flat = (it * 256 + t) * 8;
        int n = flat >> 7, k = flat & 127;
        uint4 v = *(const uint4*)(WT + flat);
        *(uint4*)(&sW[n * 136 + k]) = v;
    }
    #pragma unroll
    for (int it = 0; it < 4; ++it) {
        int flat = (it * 256 + t) * 8;
        int r = flat >> 7, cc = flat & 127;
        int row = row0 + r; if (row > M - 1) row = M - 1;
        const float* p = x + (size_t)row * 128 + cc;
        float4 f0 = *(const float4*)p;
        float4 f1 = *(const float4*)(p + 4);
        ushort_t tmp[8] __attribute__((aligned(16)));
        tmp[0] = f2b(f0.x); tmp[1] = f2b(f0.y); tmp[2] = f2b(f0.z); tmp[3] = f2b(f0.w);
        tmp[4] = f2b(f1.x); tmp[5] = f2b(f1.y); tmp[6] = f2b(f1.z); tmp[7] = f2b(f1.w);
        *(uint4*)(&sA[r * 136 + cc]) = *(const uint4*)tmp;
    }
    __syncthreads();
    int w = t >> 6, lane = t & 63;
    int m = lane & 15, quad = lane >> 4;
    f32x4 acc[8] = {};
    #pragma unroll
    for (int k0 = 0; k0 < 128; k0 += 32) {
        short8 af = *(const short8*)(&sA[(w * 16 + m) * 136 + k0 + quad * 8]);
        #pragma unroll
        for (int tt = 0; tt < 8; ++tt) {
            short8 bf = *(const short8*)(&sW[(tt * 16 + m) * 136 + k0 + quad * 8]);
            acc[tt] = __builtin_amdgcn_mfma_f32_16x16x32_bf16(af, bf, acc[tt], 0, 0, 0);
        }
    }
    #pragma unroll
    for (int r = 0; r < 4; ++r) {
        int row = row0 + w * 16 + quad * 4 + r;
        if (row < M) {
            #pragma unroll
            for (int tt = 0; tt < 8; ++tt)
                xt[(size_t)row * 128 + tt * 16 + m] = f2b(acc[tt][r]);
        }
    }
}

// ---- bucket histogram (blocks < nch) + W transpose (2 extra blocks) -----
__global__ __launch_bounds__(256) void k_histT(const int* __restrict__ ei, int E,
                                               unsigned N, int* __restrict__ bhist,
                                               int BSH, int NB, int nch,
                                               const float* __restrict__ W1,
                                               const float* __restrict__ W2,
                                               ushort_t* __restrict__ WT) {
    __shared__ int lh[256];
    int t = threadIdx.x;
    int b = blockIdx.x;
    if (b >= nch) {
        const float* src = (b == nch) ? W1 : W2;
        ushort_t* dst = WT + (b - nch) * 16384;
        for (int i = t; i < 16384; i += 256) {
            int n = i >> 7, k = i & 127;
            dst[i] = f2b(src[k * 128 + n]);   // WT[n][k] = W[k][n]
        }
        return;
    }
    for (int q = t; q < NB; q += 256) lh[q] = 0;
    int is64 = detect64(ei, t);   // includes __syncthreads
    int e0 = b * 4096;
    #pragma unroll
    for (int i = 0; i < 16; ++i) {
        int e = e0 + i * 256 + t;
        if (e < E) {
            int d = is64 ? (int)((const long long*)ei)[E + e] : ei[E + e];
            if ((unsigned)d < N) atomicAdd(&lh[d >> BSH], 1);
        }
    }
    __syncthreads();
    for (int q = t; q < NB; q += 256) { int v = lh[q]; if (v) atomicAdd(&bhist[q], v); }
}

// ---- fused: bucket scatter (blocks < nch) || GEMM1 part A (rest) --------
// Bucket blocks compute bkbase locally (LDS scan of bhist); bkcur is a
// zero-initialized DELTA cursor. Scatter stores (s,d) as ONE 8B int2.
__global__ __launch_bounds__(256) void k_bg(const int* __restrict__ ei, int E,
                                            unsigned N, const int* __restrict__ bhist,
                                            int* __restrict__ bkcur,
                                            int2* __restrict__ bsd,
                                            int BSH, int NB, int nch,
                                            const float* __restrict__ x,
                                            const ushort_t* __restrict__ WT,
                                            ushort_t* __restrict__ xt, int M) {
    __shared__ __align__(16) int smem[13056];   // 52224 B union
    int t = threadIdx.x;
    int b = blockIdx.x;

    if (b < nch) {
        int* lss = smem;             // [4096]
        int* ldd = smem + 4096;      // [4096]
        int* lhist = smem + 8192;    // [256]
        int* lcur = smem + 8448;     // [256]
        int* sbk = smem + 8704;      // [256] exclusive scan of bhist
        int e0 = b * 4096;
        // local exclusive scan of bhist
        int hv = (t < NB) ? bhist[t] : 0;
        sbk[t] = hv;
        for (int o = 1; o < 256; o <<= 1) {
            __syncthreads();
            int v = (t >= o) ? sbk[t - o] : 0;
            __syncthreads();
            sbk[t] += v;
        }
        __syncthreads();
        sbk[t] -= hv;                // exclusive
        for (int q = t; q < NB; q += 256) lhist[q] = 0;
        int is64 = detect64(ei, t);  // includes __syncthreads
        #pragma unroll
        for (int i = 0; i < 16; ++i) {
            int idx = i * 256 + t, e = e0 + idx;
            int s = -1, d = -1;
            if (e < E) {
                load_edge(ei, e, E, is64, s, d);
                if (!((unsigned)s < N && (unsigned)d < N)) d = -1;
            }
            lss[idx] = s; ldd[idx] = d;
            if (d >= 0) atomicAdd(&lhist[d >> BSH], 1);
        }
        __syncthreads();
        for (int q = t; q < NB; q += 256) {
            int v = lhist[q];
            lcur[q] = v ? (sbk[q] + atomicAdd(&bkcur[q], v)) : 0;
        }
        __syncthreads();
        #pragma unroll
        for (int i = 0; i < 16; ++i) {
            int idx = i * 256 + t;
            int d = ldd[idx];
            if (d >= 0) {
                int p = atomicAdd(&lcur[d >> BSH], 1);
                int2 pr; pr.x = lss[idx]; pr.y = d;
                bsd[p] = pr;                      // single 8B store
            }
        }
    } else {
        gemm1_block(x, WT, xt, M, (b - nch) * 64, smem, t);
    }
}

// ---- fused count + padded-scan/assign + fill (blocks < NB) || GEMM1 B ---
// caf blocks compute bkbase[b] locally from bhist; s1 = bkbase[b]+bhist[b].
// Lists padded to 8 with SELF entries; cnt stores TRUE count.
// Bucket b's srcs segment starts at bkbase[b] + b*(7<<BSH).
__global__ __launch_bounds__(256) void k_caf(const int2* __restrict__ bsd,
                                             const int* __restrict__ bhist,
                                             int N, int BSH, int NB,
                                             int* __restrict__ pos,
                                             int* __restrict__ cnt,
                                             float* __restrict__ dinv,
                                             int* __restrict__ srcs,
                                             const float* __restrict__ x,
                                             const ushort_t* __restrict__ WT,
                                             ushort_t* __restrict__ xt, int M,
                                             int GH1) {
    __shared__ __align__(16) int smem[13056];   // union with gemm branch
    int t = threadIdx.x;
    int b = blockIdx.x;
    if (b >= NB) {
        gemm1_block(x, WT, xt, M, (GH1 + b - NB) * 64, smem, t);
        return;
    }
    int* lc = smem;          // [512] counts, then fill cursors
    int* sc = smem + 512;    // [512] scans
    __shared__ int sBase, sCnt;
    int nbase = b << BSH;
    int nn = min(1 << BSH, N - nbase);

    // local exclusive scan of bhist -> bkbase[b]
    int hv = (t < NB) ? bhist[t] : 0;
    sc[t] = hv;
    for (int o = 1; o < 256; o <<= 1) {
        __syncthreads();
        int v = (t >= o) ? sc[t - o] : 0;
        __syncthreads();
        sc[t] += v;
    }
    __syncthreads();
    if (t == b) { sBase = sc[b] - hv; sCnt = hv; }   // t==b < NB <= 256
    __syncthreads();
    int s0 = sBase, s1 = sBase + sCnt;
    int segbase = sBase + b * (7 << BSH);

    lc[t] = 0; lc[t + 256] = 0;
    __syncthreads();
    for (int i = s0 + t; i < s1; i += 256) atomicAdd(&lc[bsd[i].y - nbase], 1);
    __syncthreads();

    int c0 = (t < nn) ? lc[t] : 0;
    int c1 = (t + 256 < nn) ? lc[t + 256] : 0;
    int p0 = (c0 + 7) & ~7;                // pad each list to multiple of 8
    int p1 = (c1 + 7) & ~7;
    sc[t] = p0; sc[t + 256] = p1;
    __syncthreads();
    for (int o = 1; o < 512; o <<= 1) {
        int v0 = (t >= o) ? sc[t - o] : 0;
        int v1 = (t + 256 >= o) ? sc[t + 256 - o] : 0;
        __syncthreads();
        sc[t] += v0; sc[t + 256] += v1;
        __syncthreads();
    }
    if (t < nn) {
        int st = segbase + sc[t] - p0;
        pos[nbase + t] = st;
        cnt[nbase + t] = c0;                       // TRUE count
        dinv[nbase + t] = rsqrtf((float)c0 + 1.0f);
        for (int q = c0; q < p0; ++q) srcs[st + q] = nbase + t;  // self pads
        lc[t] = st;
    }
    if (t + 256 < nn) {
        int st = segbase + sc[t + 256] - p1;
        pos[nbase + t + 256] = st;
        cnt[nbase + t + 256] = c1;
        dinv[nbase + t + 256] = rsqrtf((float)c1 + 1.0f);
        for (int q = c1; q < p1; ++q) srcs[st + q] = nbase + t + 256;
        lc[t + 256] = st;
    }
    __syncthreads();
    for (int i = s0 + t; i < s1; i += 256) {
        int2 pr = bsd[i];                          // single 8B load
        int p = atomicAdd(&lc[pr.y - nbase], 1);
        srcs[p] = pr.x;
    }
}

// ---- GEMM (standalone, layer 2): C = bf16(dinv * (A_bf16 @ W)) ----------
__global__ __launch_bounds__(256) void k_gemm2(const ushort_t* __restrict__ A,
                                               const ushort_t* __restrict__ WT,
                                               ushort_t* __restrict__ C,
                                               const float* __restrict__ dinv, int M) {
    __shared__ __align__(16) ushort_t sA[64 * 136];
    __shared__ __align__(16) ushort_t sW[128 * 136];
    int t = threadIdx.x;
    int row0 = blockIdx.x * 64;
    #pragma unroll
    for (int it = 0; it < 8; ++it) {
        int flat = (it * 256 + t) * 8;
        int n = flat >> 7, k = flat & 127;
        uint4 v = *(const uint4*)(WT + flat);
        *(uint4*)(&sW[n * 136 + k]) = v;
    }
    #pragma unroll
    for (int it = 0; it < 4; ++it) {
        int flat = (it * 256 + t) * 8;
        int r = flat >> 7, cc = flat & 127;
        int row = row0 + r; if (row > M - 1) row = M - 1;
        us8v v = *(const us8v*)(A + ((size_t)row << 7) + cc);
        *(us8v*)(&sA[r * 136 + cc]) = v;
    }
    __syncthreads();
    int w = t >> 6, lane = t & 63;
    int m = lane & 15, quad = lane >> 4;
    f32x4 acc[8] = {};
    #pragma unroll
    for (int k0 = 0; k0 < 128; k0 += 32) {
        short8 af = *(const short8*)(&sA[(w * 16 + m) * 136 + k0 + quad * 8]);
        #pragma unroll
        for (int tt = 0; tt < 8; ++tt) {
            short8 bf = *(const short8*)(&sW[(tt * 16 + m) * 136 + k0 + quad * 8]);
            acc[tt] = __builtin_amdgcn_mfma_f32_16x16x32_bf16(af, bf, acc[tt], 0, 0, 0);
        }
    }
    #pragma unroll
    for (int r = 0; r < 4; ++r) {
        int row = row0 + w * 16 + quad * 4 + r;
        if (row < M) {
            float dd = dinv[row];
            #pragma unroll
            for (int tt = 0; tt < 8; ++tt)
                C[(size_t)row * 128 + tt * 16 + m] = f2b(dd * acc[tt][r]);
        }
    }
}

// ---- Aggregation (R9-proven: pad-8, 2-deep pipeline, 4x16 us8) ----------
// WEI=true  (layer 1): o = dd*sum(dinv[s]*xt[s]) + (1-k)*dd*dd*xt[d] + b
// WEI=false (layer 2): o = dd*(sum + (1-k)*xt[d]) + b
template <bool OBF, bool WEI>
__global__ __launch_bounds__(256) void k_agg(const ushort_t* __restrict__ xt,
                                             const float* __restrict__ bias,
                                             void* __restrict__ outp,
                                             const int* __restrict__ pos,
                                             const int* __restrict__ cnts,
                                             const float* __restrict__ dinv,
                                             const int* __restrict__ srcs, int N) {
    int lane = threadIdx.x & 63;
    int slot = lane >> 4, j = lane & 15;
    int d = (blockIdx.x << 2) + (threadIdx.x >> 6);
    if (d >= N) return;
    int c = cnts[d];                        // true count
    int cn = (c + 7) & ~7;                  // padded loop bound
    float kpad = (float)(cn - c);
    int start = pos[d];
    float dd = dinv[d];
    float selfc = WEI ? (1.f - kpad) * dd * dd : (1.f - kpad) * dd;
    us8v vs = *(const us8v*)(xt + ((size_t)d << 7) + (j << 3));
    float4 bb0 = *(const float4*)(bias + (j << 3));
    float4 bb1 = *(const float4*)(bias + (j << 3) + 4);

    float a0 = 0.f, a1 = 0.f, a2 = 0.f, a3 = 0.f;
    float a4 = 0.f, a5 = 0.f, a6 = 0.f, a7 = 0.f;

    for (int base = 0; base < cn; base += 64) {
        int n = cn - base; if (n > 64) n = 64;   // multiple of 8
        int sv = 0; float wv = 1.f;
        if (lane < n) {
            sv = srcs[start + base + lane];
            if (WEI) wv = dinv[sv];
        }
        int s0 = __shfl(sv, slot);
        int s1 = __shfl(sv, 4 + slot);
        float w0 = WEI ? __shfl(wv, slot) : 1.f;
        float w1 = WEI ? __shfl(wv, 4 + slot) : 1.f;
        us8v v0 = *(const us8v*)(xt + ((size_t)s0 << 7) + (j << 3));
        us8v v1 = *(const us8v*)(xt + ((size_t)s1 << 7) + (j << 3));
        for (int cc = 8; cc < n; cc += 8) {
            int t0 = __shfl(sv, cc + slot);
            int t1 = __shfl(sv, cc + 4 + slot);
            float u0 = WEI ? __shfl(wv, cc + slot) : 1.f;
            float u1 = WEI ? __shfl(wv, cc + 4 + slot) : 1.f;
            us8v m0 = *(const us8v*)(xt + ((size_t)t0 << 7) + (j << 3));
            us8v m1 = *(const us8v*)(xt + ((size_t)t1 << 7) + (j << 3));
            a0 += w0 * b2f(v0[0]); a1 += w0 * b2f(v0[1]);
            a2 += w0 * b2f(v0[2]); a3 += w0 * b2f(v0[3]);
            a4 += w0 * b2f(v0[4]); a5 += w0 * b2f(v0[5]);
            a6 += w0 * b2f(v0[6]); a7 += w0 * b2f(v0[7]);
            a0 += w1 * b2f(v1[0]); a1 += w1 * b2f(v1[1]);
            a2 += w1 * b2f(v1[2]); a3 += w1 * b2f(v1[3]);
            a4 += w1 * b2f(v1[4]); a5 += w1 * b2f(v1[5]);
            a6 += w1 * b2f(v1[6]); a7 += w1 * b2f(v1[7]);
            v0 = m0; v1 = m1; w0 = u0; w1 = u1;
        }
        a0 += w0 * b2f(v0[0]); a1 += w0 * b2f(v0[1]);
        a2 += w0 * b2f(v0[2]); a3 += w0 * b2f(v0[3]);
        a4 += w0 * b2f(v0[4]); a5 += w0 * b2f(v0[5]);
        a6 += w0 * b2f(v0[6]); a7 += w0 * b2f(v0[7]);
        a0 += w1 * b2f(v1[0]); a1 += w1 * b2f(v1[1]);
        a2 += w1 * b2f(v1[2]); a3 += w1 * b2f(v1[3]);
        a4 += w1 * b2f(v1[4]); a5 += w1 * b2f(v1[5]);
        a6 += w1 * b2f(v1[6]); a7 += w1 * b2f(v1[7]);
    }
    a0 += __shfl_xor(a0, 32); a1 += __shfl_xor(a1, 32);
    a2 += __shfl_xor(a2, 32); a3 += __shfl_xor(a3, 32);
    a4 += __shfl_xor(a4, 32); a5 += __shfl_xor(a5, 32);
    a6 += __shfl_xor(a6, 32); a7 += __shfl_xor(a7, 32);
    a0 += __shfl_xor(a0, 16); a1 += __shfl_xor(a1, 16);
    a2 += __shfl_xor(a2, 16); a3 += __shfl_xor(a3, 16);
    a4 += __shfl_xor(a4, 16); a5 += __shfl_xor(a5, 16);
    a6 += __shfl_xor(a6, 16); a7 += __shfl_xor(a7, 16);

    if (slot == 0) {
        float o0 = dd * a0 + selfc * b2f(vs[0]) + bb0.x;
        float o1 = dd * a1 + selfc * b2f(vs[1]) + bb0.y;
        float o2 = dd * a2 + selfc * b2f(vs[2]) + bb0.z;
        float o3 = dd * a3 + selfc * b2f(vs[3]) + bb0.w;
        float o4 = dd * a4 + selfc * b2f(vs[4]) + bb1.x;
        float o5 = dd * a5 + selfc * b2f(vs[5]) + bb1.y;
        float o6 = dd * a6 + selfc * b2f(vs[6]) + bb1.z;
        float o7 = dd * a7 + selfc * b2f(vs[7]) + bb1.w;
        if (OBF) {
            ushort_t tmp[8] __attribute__((aligned(16)));
            tmp[0] = f2b(o0); tmp[1] = f2b(o1); tmp[2] = f2b(o2); tmp[3] = f2b(o3);
            tmp[4] = f2b(o4); tmp[5] = f2b(o5); tmp[6] = f2b(o6); tmp[7] = f2b(o7);
            *(us8v*)((ushort_t*)outp + ((size_t)d << 7) + (j << 3)) = *(const us8v*)tmp;
        } else {
            float4 q0 = { o0, o1, o2, o3 };
            float4 q1 = { o4, o5, o6, o7 };
            float4* po = (float4*)((float*)outp + ((size_t)d << 7) + (j << 3));
            po[0] = q0; po[1] = q1;
        }
    }
}

// ---- launch -------------------------------------------------------------

extern "C" void kernel_launch(void* const* d_in, const int* in_sizes, int n_in,
                              void* d_out, int out_size, void* d_ws, size_t ws_size,
                              hipStream_t stream) {
    const float* x  = (const float*)d_in[0];   // [N,128] f32
    const int*   ei = (const int*)d_in[1];     // [2,E] int32/int64 (detected)
    const float* W1 = (const float*)d_in[2];   // [128,128] f32
    const float* b1 = (const float*)d_in[3];   // [128] f32
    const float* W2 = (const float*)d_in[4];
    const float* b2 = (const float*)d_in[5];
    float* out = (float*)d_out;                // [N,128] f32

    const int N = in_sizes[0] / 128;
    const int E = in_sizes[1] / 2;

    // bucket size 2^BSH nodes, NB <= 256 buckets (N=100000 -> BSH=9, NB=196)
    int BSH = 9;
    int NB = (N + (1 << BSH) - 1) >> BSH;
    while (NB > 256) { BSH++; NB = (N + (1 << BSH) - 1) >> BSH; }

    char* ws = (char*)d_ws;
    size_t o = 0;
    auto take = [&](size_t bytes) { size_t r = o; o = (o + bytes + 255) & ~(size_t)255; return r; };
    size_t o_bhist  = take(256 * 4);
    size_t o_bkcur  = take(256 * 4);
    size_t zero_end = o;                  // memset: bhist + bkcur (delta cursor)
    size_t o_cnt    = take((size_t)N * 4);
    size_t o_pos    = take((size_t)N * 4);
    size_t o_dinv   = take((size_t)N * 4);
    size_t o_srcs   = take(((size_t)E + (size_t)NB * (7 << BSH) + 64) * 4);
    size_t o_WT     = take(2 * 128 * 128 * 2);
    size_t big_sz   = (size_t)E * 8 > (size_t)N * 256 ? (size_t)E * 8 : (size_t)N * 256;
    size_t o_big    = take(big_sz);
    (void)ws_size;

    int*      bhist  = (int*)(ws + o_bhist);
    int*      bkcur  = (int*)(ws + o_bkcur);
    int*      cnt    = (int*)(ws + o_cnt);
    int*      pos    = (int*)(ws + o_pos);
    float*    dinv   = (float*)(ws + o_dinv);
    int*      srcs   = (int*)(ws + o_srcs);
    ushort_t* WT     = (ushort_t*)(ws + o_WT);
    int2*     bsd    = (int2*)(ws + o_big);          // CSR-build phase only
    ushort_t* xt2    = (ushort_t*)(ws + o_big);      // layer 2 (bsd dead)
    // d_out split: xt1 (lower N*256 B) + hbf (upper N*256 B); both dead
    // before agg2 overwrites d_out with the final f32 output.
    ushort_t* xt1    = (ushort_t*)d_out;
    ushort_t* hbf    = (ushort_t*)d_out + (size_t)N * 128;

    hipMemsetAsync(d_ws, 0, zero_end, stream);

    int nch = (E + 4095) / 4096;
    int gG  = (N + 63) / 64;
    int GH1 = (gG + 1) / 2;                // gemm1 rows in k_bg
    int GH2 = gG - GH1;                    // gemm1 rows in k_caf dispatch
    int gA  = (N + 3) / 4;
    unsigned Nu = (unsigned)N;

    // hist (LDS only) + W transpose
    k_histT<<<nch + 2, 256, 0, stream>>>(ei, E, Nu, bhist, BSH, NB, nch, W1, W2, WT);
    // bucket scatter (in-block bhist scan, delta cursor, 8B pair) || GEMM1 A
    k_bg<<<nch + GH1, 256, 0, stream>>>(ei, E, Nu, bhist, bkcur, bsd, BSH, NB,
                                        nch, x, WT, xt1, N);
    // count+assign+fill (8B pair reads) || GEMM1 part B
    k_caf<<<NB + GH2, 256, 0, stream>>>(bsd, bhist, N, BSH, NB, pos, cnt, dinv,
                                        srcs, x, WT, xt1, N, GH1);

    // layer 1: hbf = bf16(agg_weighted(xt1) + b1)
    k_agg<true, true><<<gA, 256, 0, stream>>>(xt1, b1, hbf, pos, cnt, dinv, srcs, N);
    // layer 2: xt2 = bf16(dinv * (hbf @ W2)); out = agg(xt2) + b2 (f32)
    k_gemm2<<<gG, 256, 0, stream>>>(hbf, WT + 16384, xt2, dinv, N);
    k_agg<false, false><<<gA, 256, 0, stream>>>(xt2, b2, out, pos, cnt, dinv, srcs, N);
}